// Round 18
// baseline (101.031 us; speedup 1.0000x reference)
//
#include <hip/hip_runtime.h>

#define N_NODES 100000
#define N_EDGES 1000000
#define D 64
#define NCLS 10
#define NTILES (N_NODES / 16)   // 6250, exact (even -> 2 tiles/block exact)

#define NBUCK 196            // buckets of 512 nodes: bucket = dst >> 9
#define BNODES 512
#define P_BLOCKS 256         // partition blocks
#define P_EPB 3907           // edges per partition block; 256*3907 >= 1M

#define CVT_BLOCKS (N_NODES * D / 4 / 256)   // 6250, exact

typedef __attribute__((ext_vector_type(8))) short bf16x8;   // 8 bf16 = 4 VGPR
typedef __attribute__((ext_vector_type(4))) float f32x4;

// round-to-nearest-even f32 -> bf16 bits
__device__ __forceinline__ unsigned short f2bf(float x) {
    unsigned int u = __float_as_uint(x);
    u += 0x7fffu + ((u >> 16) & 1u);
    return (unsigned short)(u >> 16);
}
__device__ __forceinline__ unsigned int pack2bf(float lo, float hi) {
    return (unsigned int)f2bf(lo) | ((unsigned int)f2bf(hi) << 16);
}
__device__ __forceinline__ float blo(unsigned int u) { return __uint_as_float(u << 16); }
__device__ __forceinline__ float bhi(unsigned int u) { return __uint_as_float(u & 0xffff0000u); }

// ---------------------------------------------------------------------------
// Kernel 1 (merged): blocks 0..255 -> per-(block,bucket) edge histogram;
// then prep blocks (bf16 table + weight packs); last block zeroes the
// sentinel row N_NODES of both feature tables AND the sorted_src pad.
// ---------------------------------------------------------------------------
__global__ __launch_bounds__(256) void hist_prep(const int* __restrict__ dst,
                                                 int* __restrict__ histG,
                                                 const float* __restrict__ x,
                                                 const float* __restrict__ W1l,
                                                 const float* __restrict__ W1r,
                                                 const float* __restrict__ W2l,
                                                 const float* __restrict__ W2r,
                                                 const float* __restrict__ Wout,
                                                 unsigned short* __restrict__ xb,
                                                 unsigned short* __restrict__ h1b,
                                                 int* __restrict__ sorted_src,
                                                 unsigned int* __restrict__ pB1,
                                                 unsigned int* __restrict__ pB2,
                                                 unsigned int* __restrict__ pBo) {
    const int tid = threadIdx.x;
    if (blockIdx.x < P_BLOCKS) {                 // ---- edge histogram ----
        __shared__ int lh[256];
        lh[tid] = 0;
        __syncthreads();
        const int e0 = blockIdx.x * P_EPB;
        int ecnt = N_EDGES - e0;
        if (ecnt > P_EPB) ecnt = P_EPB;
        if (ecnt < 0) ecnt = 0;
        for (int i = tid; i < ecnt; i += 256)
            atomicAdd(&lh[dst[e0 + i] >> 9], 1);   // LDS atomic
        __syncthreads();
        if (tid < NBUCK) histG[tid * P_BLOCKS + blockIdx.x] = lh[tid];
        return;
    }
    const int b = blockIdx.x - P_BLOCKS;
    if (b < CVT_BLOCKS) {                        // ---- x -> bf16 table ----
        int i = b * 256 + tid;                   // float4 index, exact bound
        float4 v = ((const float4*)x)[i];
        ushort4 o;
        o.x = f2bf(v.x); o.y = f2bf(v.y); o.z = f2bf(v.z); o.w = f2bf(v.w);
        ((ushort4*)xb)[i] = o;
    } else if (b < CVT_BLOCKS + 32) {            // ---- SAGE weight packs ----
        int wsel = (b - CVT_BLOCKS) >> 4;
        const float* Wl = wsel ? W2l : W1l;
        const float* Wr = wsel ? W2r : W1r;
        unsigned int* pB = wsel ? pB2 : pB1;
        int idx = ((b - CVT_BLOCKS) & 15) * 256 + tid;   // 0..4095
        int r    = idx & 3;
        int lane = (idx >> 2) & 63;
        int n    = (idx >> 8) & 3;
        int t    = idx >> 10;
        int j  = n * 16 + (lane & 15);
        int k0 = t * 32 + ((lane >> 4) << 3) + 2 * r;
        float lo = (k0 < 64) ? Wl[j * 64 + k0] : Wr[j * 64 + (k0 - 64)];
        float hi = (k0 + 1 < 64) ? Wl[j * 64 + k0 + 1] : Wr[j * 64 + (k0 - 63)];
        pB[idx] = pack2bf(lo, hi);
    } else if (b < CVT_BLOCKS + 34) {            // ---- W_out pack ----
        int idx = (b - CVT_BLOCKS - 32) * 256 + tid;
        if (idx < 512) {
            int r    = idx & 3;
            int lane = (idx >> 2) & 63;
            int t    = idx >> 8;
            int j  = lane & 15;
            int k0 = t * 32 + ((lane >> 4) << 3) + 2 * r;
            float lo = (j < NCLS) ? Wout[j * 64 + k0] : 0.f;
            float hi = (j < NCLS) ? Wout[j * 64 + k0 + 1] : 0.f;
            pBo[idx] = pack2bf(lo, hi);
        }
    } else {                                     // ---- sentinels ----
        if (tid < 64) {
            xb[N_NODES * 64 + tid] = 0;
            h1b[N_NODES * 64 + tid] = 0;
        }
        if (tid < 8) sorted_src[N_EDGES + tid] = 0;   // pad: clamp-free reads
    }
}

// ---------------------------------------------------------------------------
// Kernel 2 (merged scan): one block per bucket row. Each block redundantly
// computes all 196 row sums (int4 strip loads, L2-resident ~200KB), scans
// them in LDS for its row offset, then scans its own 256-entry row -> ebase.
// ---------------------------------------------------------------------------
__global__ __launch_bounds__(256) void scan_ebase(const int* __restrict__ histG,
                                                  int* __restrict__ ebase) {
    __shared__ int p[256];
    __shared__ int s[256];
    const int t = threadIdx.x;
    const int b = blockIdx.x;
    int rs = 0;
    if (t < NBUCK) {
        const int4* rp = (const int4*)(histG + t * P_BLOCKS);
#pragma unroll 8
        for (int i = 0; i < P_BLOCKS / 4; ++i) {
            int4 v = rp[i];
            rs += (v.x + v.y) + (v.z + v.w);
        }
    }
    p[t] = rs;
    __syncthreads();
    for (int st = 1; st < 256; st <<= 1) {
        int u = (t >= st) ? p[t - st] : 0;
        __syncthreads();
        p[t] += u;
        __syncthreads();
    }
    const int rowOff = (b > 0) ? p[b - 1] : 0;
    int v = histG[b * P_BLOCKS + t];
    s[t] = v;
    __syncthreads();
    for (int st = 1; st < 256; st <<= 1) {
        int u = (t >= st) ? s[t - st] : 0;
        __syncthreads();
        s[t] += u;
        __syncthreads();
    }
    ebase[b * P_BLOCKS + t] = s[t] - v + rowOff;
}

// ---------------------------------------------------------------------------
// Kernel 3: partition edges into bucket-sorted packed array.
// Packed record: (src<<9)|(dst&511).
// ---------------------------------------------------------------------------
__global__ __launch_bounds__(256) void edge_partition(const int* __restrict__ src,
                                                      const int* __restrict__ dst,
                                                      const int* __restrict__ ebase,
                                                      unsigned int* __restrict__ pairs) {
    __shared__ int s[256];
    __shared__ int lbase[256];
    __shared__ int lcur[256];
    __shared__ uint2 buf[P_EPB];     // 31.2 KB
    const int tid = threadIdx.x;
    const int e0 = blockIdx.x * P_EPB;
    int ecnt = N_EDGES - e0;
    if (ecnt > P_EPB) ecnt = P_EPB;
    if (ecnt < 0) ecnt = 0;

    lcur[tid] = 0;
    __syncthreads();
    for (int i = tid; i < ecnt; i += 256)
        atomicAdd(&lcur[dst[e0 + i] >> 9], 1);
    __syncthreads();
    int v = lcur[tid];
    s[tid] = v;
    __syncthreads();
    for (int st = 1; st < 256; st <<= 1) {
        int u = (tid >= st) ? s[tid - st] : 0;
        __syncthreads();
        s[tid] += u;
        __syncthreads();
    }
    int excl = s[tid] - v;
    lbase[tid] = excl;
    lcur[tid] = excl;
    __syncthreads();
    for (int i = tid; i < ecnt; i += 256) {
        int d = dst[e0 + i], sv = src[e0 + i];
        int p = atomicAdd(&lcur[d >> 9], 1);
        buf[p] = make_uint2((unsigned)sv, (unsigned)d);
    }
    __syncthreads();
    for (int i = tid; i < ecnt; i += 256) {
        uint2 pr = buf[i];
        int bk = (int)(pr.y >> 9);
        pairs[ebase[bk * P_BLOCKS + blockIdx.x] + (i - lbase[bk])] =
            (pr.x << 9) | (pr.y & 511u);
    }
}

// ---------------------------------------------------------------------------
// Kernel 4: per-bucket node hist + scan -> row_ptr; LDS-cursor scatter of
// src into sorted_src.
// ---------------------------------------------------------------------------
__global__ __launch_bounds__(256) void bucket_csr(const unsigned int* __restrict__ pairs,
                                                  const int* __restrict__ ebase,
                                                  int* __restrict__ row_ptr,
                                                  int* __restrict__ sorted_src) {
    __shared__ int h[BNODES];    // counts -> exclusive scan -> cursors
    __shared__ int part[256];
    const int tid = threadIdx.x;
    const int b = blockIdx.x;
    const int base = ebase[b * P_BLOCKS];
    const int next = (b == NBUCK - 1) ? N_EDGES : ebase[(b + 1) * P_BLOCKS];
    const int cnt = next - base;
    const int n0 = b * BNODES;

    h[tid] = 0; h[tid + 256] = 0;
    __syncthreads();
    for (int i = tid; i < cnt; i += 256)
        atomicAdd(&h[pairs[base + i] & 511u], 1);
    __syncthreads();
    int a0 = h[2 * tid], a1 = h[2 * tid + 1];
    part[tid] = a0 + a1;
    __syncthreads();
    for (int st = 1; st < 256; st <<= 1) {
        int u = (tid >= st) ? part[tid - st] : 0;
        __syncthreads();
        part[tid] += u;
        __syncthreads();
    }
    int eb = part[tid] - (a0 + a1);          // exclusive base of node pair
    h[2 * tid] = eb;
    h[2 * tid + 1] = eb + a0;
    int node0 = n0 + 2 * tid;
    if (node0 <= N_NODES) row_ptr[node0] = base + eb;
    if (node0 + 1 <= N_NODES) row_ptr[node0 + 1] = base + eb + a0;
    __syncthreads();
    for (int i = tid; i < cnt; i += 256) {
        unsigned int pr = pairs[base + i];
        int p = atomicAdd(&h[pr & 511u], 1);
        sorted_src[base + p] = (int)(pr >> 9);
    }
}

// ---------------------------------------------------------------------------
// Gather core: ONE NODE PER 8-LANE GROUP, 8 nodes per wave in parallel.
// Lane (grp, q) accumulates features 8q..8q+7 of node grp -> NO cross-lane
// reduce; group writes its 128B mean row directly. Per-group loop bound
// (finished groups exec-masked -> no memory requests). sorted_src is
// zero-padded -> clamp-free idx loads. Invalid slots redirect the index
// to the zero sentinel row.
// ---------------------------------------------------------------------------
__device__ __forceinline__ void gather8g(
        const uint4* __restrict__ featb4,   // bf16 rows as [N][8] uint4
        const int* __restrict__ row_ptr,
        const int* __restrict__ sorted_src,
        int node0, int l, unsigned short mt[16][72], int mrow0) {
    const int grp = l >> 3;     // node slot 0..7
    const int q   = l & 7;      // uint4 within row (feats 8q..8q+7)

    int rp = 0;
    if (l <= 8) rp = row_ptr[node0 + l];   // 9 boundaries, one load
    const int start = __shfl(rp, grp);
    const int end   = __shfl(rp, grp + 1);
    const int deg   = end - start;

    float a0 = 0.f, a1 = 0.f, a2 = 0.f, a3 = 0.f,
          a4 = 0.f, a5 = 0.f, a6 = 0.f, a7 = 0.f;
    for (int j = 0; j < deg; j += 4) {     // per-group bound; masked exit
        int e0 = start + j, e1 = e0 + 1, e2 = e0 + 2, e3 = e0 + 3;
        int s0 = sorted_src[e0];           // pad-safe, no clamp
        int s1 = sorted_src[e1];
        int s2 = sorted_src[e2];
        int s3 = sorted_src[e3];
        int i0 = (e0 < end) ? s0 : N_NODES;   // sentinel row = zeros
        int i1 = (e1 < end) ? s1 : N_NODES;
        int i2 = (e2 < end) ? s2 : N_NODES;
        int i3 = (e3 < end) ? s3 : N_NODES;
        uint4 w0 = featb4[i0 * 8 + q];
        uint4 w1 = featb4[i1 * 8 + q];
        uint4 w2 = featb4[i2 * 8 + q];
        uint4 w3 = featb4[i3 * 8 + q];
        a0 += (blo(w0.x) + blo(w1.x)) + (blo(w2.x) + blo(w3.x));
        a1 += (bhi(w0.x) + bhi(w1.x)) + (bhi(w2.x) + bhi(w3.x));
        a2 += (blo(w0.y) + blo(w1.y)) + (blo(w2.y) + blo(w3.y));
        a3 += (bhi(w0.y) + bhi(w1.y)) + (bhi(w2.y) + bhi(w3.y));
        a4 += (blo(w0.z) + blo(w1.z)) + (blo(w2.z) + blo(w3.z));
        a5 += (bhi(w0.z) + bhi(w1.z)) + (bhi(w2.z) + bhi(w3.z));
        a6 += (blo(w0.w) + blo(w1.w)) + (blo(w2.w) + blo(w3.w));
        a7 += (bhi(w0.w) + bhi(w1.w)) + (bhi(w2.w) + bhi(w3.w));
    }

    float inv = 1.0f / fmaxf((float)deg, 1.0f);
    uint4 o;
    o.x = pack2bf(a0 * inv, a1 * inv);
    o.y = pack2bf(a2 * inv, a3 * inv);
    o.z = pack2bf(a4 * inv, a5 * inv);
    o.w = pack2bf(a6 * inv, a7 * inv);
    *(uint4*)&mt[mrow0 + grp][q << 3] = o;   // every lane writes 16B
}

// ---------------------------------------------------------------------------
// Layer 1 fused: 2 waves per tile. Gather (8 nodes/wave, group-parallel) ->
// sync -> each wave runs 2 of the tile's 4 N-tile MFMA chains.
// ---------------------------------------------------------------------------
__global__ __launch_bounds__(256) void sage_fused(
        const uint4* __restrict__ featb4,          // xb (with zero row)
        const int* __restrict__ row_ptr,
        const int* __restrict__ sorted_src,
        const unsigned int* __restrict__ packedB,
        const float* __restrict__ bias,
        unsigned short* __restrict__ outb) {
    __shared__ __align__(16) unsigned short mt[2][16][72];
    const int wv = threadIdx.x >> 6;
    const int l  = threadIdx.x & 63;
    const int ts   = wv >> 1;                 // tile slot in block
    const int half = wv & 1;                  // which 8 nodes / which 2 N-tiles
    const int tile = blockIdx.x * 2 + ts;     // grid exact (NTILES even)

    gather8g(featb4, row_ptr, sorted_src, (tile << 4) + (half << 3), l,
             mt[ts], half << 3);
    __syncthreads();

    const int col = l & 15;
    const int g   = l >> 4;
    bf16x8 af0 = *(const bf16x8*)&mt[ts][col][g << 3];
    bf16x8 af1 = *(const bf16x8*)&mt[ts][col][32 + (g << 3)];
    const unsigned int* srw = (const unsigned int*)featb4 + ((tile << 4) + col) * 32;
    bf16x8 af2 = *(const bf16x8*)(srw + (g << 2));
    bf16x8 af3 = *(const bf16x8*)(srw + 16 + (g << 2));

#pragma unroll
    for (int nn = 0; nn < 2; ++nn) {
        const int n = (half << 1) | nn;
        bf16x8 b0 = *(const bf16x8*)(packedB + (((0 * 4 + n) * 64 + l) << 2));
        bf16x8 b1 = *(const bf16x8*)(packedB + (((1 * 4 + n) * 64 + l) << 2));
        bf16x8 b2 = *(const bf16x8*)(packedB + (((2 * 4 + n) * 64 + l) << 2));
        bf16x8 b3 = *(const bf16x8*)(packedB + (((3 * 4 + n) * 64 + l) << 2));
        f32x4 a = {0.f, 0.f, 0.f, 0.f};
        a = __builtin_amdgcn_mfma_f32_16x16x32_bf16(af0, b0, a, 0, 0, 0);
        a = __builtin_amdgcn_mfma_f32_16x16x32_bf16(af1, b1, a, 0, 0, 0);
        a = __builtin_amdgcn_mfma_f32_16x16x32_bf16(af2, b2, a, 0, 0, 0);
        a = __builtin_amdgcn_mfma_f32_16x16x32_bf16(af3, b3, a, 0, 0, 0);
        const int j = (n << 4) | col;
        const float bj = bias[j];
#pragma unroll
        for (int r = 0; r < 4; ++r) {
            int node = (tile << 4) + (g << 2) + r;
            outb[node * 64 + j] = f2bf(fmaxf(a[r] + bj, 0.f));
        }
    }
}

// ---------------------------------------------------------------------------
// Layer 2 fused + output projection: same 2-wave-per-tile structure; h2
// tile assembled in LDS (both waves write their column halves), then the
// even wave of each pair runs the K=64 projection MFMAs. No h2 buffer.
// ---------------------------------------------------------------------------
__global__ __launch_bounds__(256) void sage_fused_out(
        const uint4* __restrict__ featb4,           // h1b (with zero row)
        const int* __restrict__ row_ptr,
        const int* __restrict__ sorted_src,
        const unsigned int* __restrict__ packedB,   // layer-2 weights
        const float* __restrict__ bias,             // b2
        const unsigned int* __restrict__ packedBo,  // 512 dwords
        const float* __restrict__ bout,
        float* __restrict__ out) {
    __shared__ __align__(16) unsigned short mt[2][16][72];
    __shared__ __align__(16) unsigned short ht[2][16][72];
    const int wv = threadIdx.x >> 6;
    const int l  = threadIdx.x & 63;
    const int ts   = wv >> 1;
    const int half = wv & 1;
    const int tile = blockIdx.x * 2 + ts;

    gather8g(featb4, row_ptr, sorted_src, (tile << 4) + (half << 3), l,
             mt[ts], half << 3);
    __syncthreads();

    const int col = l & 15;
    const int g   = l >> 4;
    bf16x8 af0 = *(const bf16x8*)&mt[ts][col][g << 3];
    bf16x8 af1 = *(const bf16x8*)&mt[ts][col][32 + (g << 3)];
    const unsigned int* srw = (const unsigned int*)featb4 + ((tile << 4) + col) * 32;
    bf16x8 af2 = *(const bf16x8*)(srw + (g << 2));
    bf16x8 af3 = *(const bf16x8*)(srw + 16 + (g << 2));

#pragma unroll
    for (int nn = 0; nn < 2; ++nn) {
        const int n = (half << 1) | nn;
        bf16x8 b0 = *(const bf16x8*)(packedB + (((0 * 4 + n) * 64 + l) << 2));
        bf16x8 b1 = *(const bf16x8*)(packedB + (((1 * 4 + n) * 64 + l) << 2));
        bf16x8 b2 = *(const bf16x8*)(packedB + (((2 * 4 + n) * 64 + l) << 2));
        bf16x8 b3 = *(const bf16x8*)(packedB + (((3 * 4 + n) * 64 + l) << 2));
        f32x4 a = {0.f, 0.f, 0.f, 0.f};
        a = __builtin_amdgcn_mfma_f32_16x16x32_bf16(af0, b0, a, 0, 0, 0);
        a = __builtin_amdgcn_mfma_f32_16x16x32_bf16(af1, b1, a, 0, 0, 0);
        a = __builtin_amdgcn_mfma_f32_16x16x32_bf16(af2, b2, a, 0, 0, 0);
        a = __builtin_amdgcn_mfma_f32_16x16x32_bf16(af3, b3, a, 0, 0, 0);
        const int j = (n << 4) | col;
        const float bj = bias[j];
#pragma unroll
        for (int r = 0; r < 4; ++r)
            ht[ts][(g << 2) + r][j] = f2bf(fmaxf(a[r] + bj, 0.f));
    }
    __syncthreads();

    if (half == 0) {   // even wave of each pair projects its tile
        bf16x8 bo0 = *(const bf16x8*)(packedBo + (l << 2));
        bf16x8 bo1 = *(const bf16x8*)(packedBo + ((64 + l) << 2));
        bf16x8 ha0 = *(const bf16x8*)&ht[ts][col][g << 3];
        bf16x8 ha1 = *(const bf16x8*)&ht[ts][col][32 + (g << 3)];

        f32x4 acc2 = {0.f, 0.f, 0.f, 0.f};
        acc2 = __builtin_amdgcn_mfma_f32_16x16x32_bf16(ha0, bo0, acc2, 0, 0, 0);
        acc2 = __builtin_amdgcn_mfma_f32_16x16x32_bf16(ha1, bo1, acc2, 0, 0, 0);

        if (col < NCLS) {
            float bj = bout[col];
#pragma unroll
            for (int r = 0; r < 4; ++r)
                out[((tile << 4) + (g << 2) + r) * NCLS + col] = acc2[r] + bj;
        }
    }
}

// ---------------------------------------------------------------------------
extern "C" void kernel_launch(void* const* d_in, const int* in_sizes, int n_in,
                              void* d_out, int out_size, void* d_ws, size_t ws_size,
                              hipStream_t stream) {
    const float* x   = (const float*)d_in[0];
    const int*   ei  = (const int*)d_in[1];   // [2, N_EDGES]
    const int*   src = ei;
    const int*   dst = ei + N_EDGES;
    const float* W1l = (const float*)d_in[2];
    const float* W1r = (const float*)d_in[3];
    const float* b1  = (const float*)d_in[4];
    const float* W2l = (const float*)d_in[5];
    const float* W2r = (const float*)d_in[6];
    const float* b2  = (const float*)d_in[7];
    const float* Wo  = (const float*)d_in[8];
    const float* bo  = (const float*)d_in[9];
    float* out = (float*)d_out;

    char* ws = (char*)d_ws;
    int*   histG      = (int*)(ws + 0x0000000);  // 50176 ints
    int*   ebase      = (int*)(ws + 0x0044000);  // 50176 ints
    int*   row_ptr    = (int*)(ws + 0x0080000);  // 100001 ints
    unsigned int* pairs = (unsigned int*)(ws + 0x0100000);     // 4 MB (packed)
    int*   sorted_src = (int*)(ws + 0x0500000);                // 4 MB + 32B pad
    unsigned short* xb  = (unsigned short*)(ws + 0x0900000);   // 12.8 MB + zero row
    unsigned short* h1b = (unsigned short*)(ws + 0x1540000);   // 12.8 MB + zero row
    unsigned int* packedB1 = (unsigned int*)(ws + 0x2180000);  // 16 KB
    unsigned int* packedB2 = (unsigned int*)(ws + 0x2184000);  // 16 KB
    unsigned int* packedBo = (unsigned int*)(ws + 0x2188000);  // 2 KB

    const int layer_blocks = NTILES / 2;               // 3125, exact
    const int hp_blocks    = P_BLOCKS + CVT_BLOCKS + 32 + 2 + 1;  // 6541

    // ---- CSR build + prep (4 dispatches) ----
    hist_prep<<<hp_blocks, 256, 0, stream>>>(dst, histG, x, W1l, W1r, W2l, W2r,
                                             Wo, xb, h1b, sorted_src,
                                             packedB1, packedB2, packedBo);
    scan_ebase<<<NBUCK, 256, 0, stream>>>(histG, ebase);
    edge_partition<<<P_BLOCKS, 256, 0, stream>>>(src, dst, ebase, pairs);
    bucket_csr<<<NBUCK, 256, 0, stream>>>(pairs, ebase, row_ptr, sorted_src);

    // ---- layer 1 (fused gather+MFMA, group-parallel gather) ----
    sage_fused<<<layer_blocks, 256, 0, stream>>>((const uint4*)xb, row_ptr,
                                                 sorted_src, packedB1, b1, h1b);

    // ---- layer 2 + output projection (fused) ----
    sage_fused_out<<<layer_blocks, 256, 0, stream>>>((const uint4*)h1b, row_ptr,
                                                     sorted_src, packedB2, b2,
                                                     packedBo, bo, out);
}

// Round 19
// 96.416 us; speedup vs baseline: 1.0479x; 1.0479x over previous
//
#include <hip/hip_runtime.h>

#define N_NODES 100000
#define N_EDGES 1000000
#define D 64
#define NCLS 10
#define NTILES (N_NODES / 16)   // 6250, exact (even -> 2 tiles/block exact)

#define NBUCK 196            // buckets of 512 nodes: bucket = dst >> 9
#define BNODES 512
#define P_BLOCKS 256         // partition blocks
#define P_EPB 3907           // edges per partition block; 256*3907 >= 1M

#define CVT_BLOCKS (N_NODES * D / 4 / 256)   // 6250, exact

typedef __attribute__((ext_vector_type(8))) short bf16x8;   // 8 bf16 = 4 VGPR
typedef __attribute__((ext_vector_type(4))) float f32x4;

// round-to-nearest-even f32 -> bf16 bits
__device__ __forceinline__ unsigned short f2bf(float x) {
    unsigned int u = __float_as_uint(x);
    u += 0x7fffu + ((u >> 16) & 1u);
    return (unsigned short)(u >> 16);
}
__device__ __forceinline__ unsigned int pack2bf(float lo, float hi) {
    return (unsigned int)f2bf(lo) | ((unsigned int)f2bf(hi) << 16);
}
__device__ __forceinline__ float blo(unsigned int u) { return __uint_as_float(u << 16); }
__device__ __forceinline__ float bhi(unsigned int u) { return __uint_as_float(u & 0xffff0000u); }

// ---------------------------------------------------------------------------
// Kernel 1 (merged): blocks 0..255 -> per-(block,bucket) edge histogram;
// then prep blocks (bf16 table + weight packs); last block zeroes the
// sentinel row N_NODES of both feature tables AND the sorted_src pad.
// ---------------------------------------------------------------------------
__global__ __launch_bounds__(256) void hist_prep(const int* __restrict__ dst,
                                                 int* __restrict__ histG,
                                                 const float* __restrict__ x,
                                                 const float* __restrict__ W1l,
                                                 const float* __restrict__ W1r,
                                                 const float* __restrict__ W2l,
                                                 const float* __restrict__ W2r,
                                                 const float* __restrict__ Wout,
                                                 unsigned short* __restrict__ xb,
                                                 unsigned short* __restrict__ h1b,
                                                 int* __restrict__ sorted_src,
                                                 unsigned int* __restrict__ pB1,
                                                 unsigned int* __restrict__ pB2,
                                                 unsigned int* __restrict__ pBo) {
    const int tid = threadIdx.x;
    if (blockIdx.x < P_BLOCKS) {                 // ---- edge histogram ----
        __shared__ int lh[256];
        lh[tid] = 0;
        __syncthreads();
        const int e0 = blockIdx.x * P_EPB;
        int ecnt = N_EDGES - e0;
        if (ecnt > P_EPB) ecnt = P_EPB;
        if (ecnt < 0) ecnt = 0;
        for (int i = tid; i < ecnt; i += 256)
            atomicAdd(&lh[dst[e0 + i] >> 9], 1);   // LDS atomic
        __syncthreads();
        if (tid < NBUCK) histG[tid * P_BLOCKS + blockIdx.x] = lh[tid];
        return;
    }
    const int b = blockIdx.x - P_BLOCKS;
    if (b < CVT_BLOCKS) {                        // ---- x -> bf16 table ----
        int i = b * 256 + tid;                   // float4 index, exact bound
        float4 v = ((const float4*)x)[i];
        ushort4 o;
        o.x = f2bf(v.x); o.y = f2bf(v.y); o.z = f2bf(v.z); o.w = f2bf(v.w);
        ((ushort4*)xb)[i] = o;
    } else if (b < CVT_BLOCKS + 32) {            // ---- SAGE weight packs ----
        int wsel = (b - CVT_BLOCKS) >> 4;
        const float* Wl = wsel ? W2l : W1l;
        const float* Wr = wsel ? W2r : W1r;
        unsigned int* pB = wsel ? pB2 : pB1;
        int idx = ((b - CVT_BLOCKS) & 15) * 256 + tid;   // 0..4095
        int r    = idx & 3;
        int lane = (idx >> 2) & 63;
        int n    = (idx >> 8) & 3;
        int t    = idx >> 10;
        int j  = n * 16 + (lane & 15);
        int k0 = t * 32 + ((lane >> 4) << 3) + 2 * r;
        float lo = (k0 < 64) ? Wl[j * 64 + k0] : Wr[j * 64 + (k0 - 64)];
        float hi = (k0 + 1 < 64) ? Wl[j * 64 + k0 + 1] : Wr[j * 64 + (k0 - 63)];
        pB[idx] = pack2bf(lo, hi);
    } else if (b < CVT_BLOCKS + 34) {            // ---- W_out pack ----
        int idx = (b - CVT_BLOCKS - 32) * 256 + tid;
        if (idx < 512) {
            int r    = idx & 3;
            int lane = (idx >> 2) & 63;
            int t    = idx >> 8;
            int j  = lane & 15;
            int k0 = t * 32 + ((lane >> 4) << 3) + 2 * r;
            float lo = (j < NCLS) ? Wout[j * 64 + k0] : 0.f;
            float hi = (j < NCLS) ? Wout[j * 64 + k0 + 1] : 0.f;
            pBo[idx] = pack2bf(lo, hi);
        }
    } else {                                     // ---- sentinels ----
        if (tid < 64) {
            xb[N_NODES * 64 + tid] = 0;
            h1b[N_NODES * 64 + tid] = 0;
        }
        if (tid < 8) sorted_src[N_EDGES + tid] = 0;   // pad: clamp-free reads
    }
}

// ---------------------------------------------------------------------------
// Kernel 2: per-256-chunk sums of histG rows (196 blocks).
// ---------------------------------------------------------------------------
__global__ __launch_bounds__(256) void scan_partials(const int* __restrict__ in,
                                                     int* __restrict__ blockSum) {
    __shared__ int s[256];
    s[threadIdx.x] = in[blockIdx.x * 256 + threadIdx.x];
    __syncthreads();
    for (int st = 128; st > 0; st >>= 1) {
        if (threadIdx.x < st) s[threadIdx.x] += s[threadIdx.x + st];
        __syncthreads();
    }
    if (threadIdx.x == 0) blockSum[blockIdx.x] = s[0];
}

// ---------------------------------------------------------------------------
// Kernel 3: full exclusive scan -> ebase (each block re-scans 196 row totals).
// ---------------------------------------------------------------------------
__global__ __launch_bounds__(256) void scan_final(const int* __restrict__ in,
                                                  const int* __restrict__ blockSum,
                                                  int* __restrict__ ebase) {
    __shared__ int p[256];
    __shared__ int s[256];
    const int t = threadIdx.x;
    int pv = (t < NBUCK) ? blockSum[t] : 0;
    p[t] = pv;
    __syncthreads();
    for (int st = 1; st < 256; st <<= 1) {
        int u = (t >= st) ? p[t - st] : 0;
        __syncthreads();
        p[t] += u;
        __syncthreads();
    }
    const int rowOff = (blockIdx.x > 0) ? p[blockIdx.x - 1] : 0;
    const int i = blockIdx.x * 256 + t;
    int v = in[i];
    s[t] = v;
    __syncthreads();
    for (int st = 1; st < 256; st <<= 1) {
        int u = (t >= st) ? s[t - st] : 0;
        __syncthreads();
        s[t] += u;
        __syncthreads();
    }
    ebase[i] = s[t] - v + rowOff;
}

// ---------------------------------------------------------------------------
// Kernel 4: partition edges into bucket-sorted packed array.
// Packed record: (src<<9)|(dst&511).
// ---------------------------------------------------------------------------
__global__ __launch_bounds__(256) void edge_partition(const int* __restrict__ src,
                                                      const int* __restrict__ dst,
                                                      const int* __restrict__ ebase,
                                                      unsigned int* __restrict__ pairs) {
    __shared__ int s[256];
    __shared__ int lbase[256];
    __shared__ int lcur[256];
    __shared__ uint2 buf[P_EPB];     // 31.2 KB
    const int tid = threadIdx.x;
    const int e0 = blockIdx.x * P_EPB;
    int ecnt = N_EDGES - e0;
    if (ecnt > P_EPB) ecnt = P_EPB;
    if (ecnt < 0) ecnt = 0;

    lcur[tid] = 0;
    __syncthreads();
    for (int i = tid; i < ecnt; i += 256)
        atomicAdd(&lcur[dst[e0 + i] >> 9], 1);
    __syncthreads();
    int v = lcur[tid];
    s[tid] = v;
    __syncthreads();
    for (int st = 1; st < 256; st <<= 1) {
        int u = (tid >= st) ? s[tid - st] : 0;
        __syncthreads();
        s[tid] += u;
        __syncthreads();
    }
    int excl = s[tid] - v;
    lbase[tid] = excl;
    lcur[tid] = excl;
    __syncthreads();
    for (int i = tid; i < ecnt; i += 256) {
        int d = dst[e0 + i], sv = src[e0 + i];
        int p = atomicAdd(&lcur[d >> 9], 1);
        buf[p] = make_uint2((unsigned)sv, (unsigned)d);
    }
    __syncthreads();
    for (int i = tid; i < ecnt; i += 256) {
        uint2 pr = buf[i];
        int bk = (int)(pr.y >> 9);
        pairs[ebase[bk * P_BLOCKS + blockIdx.x] + (i - lbase[bk])] =
            (pr.x << 9) | (pr.y & 511u);
    }
}

// ---------------------------------------------------------------------------
// Kernel 5: per-bucket node hist + scan -> row_ptr; LDS-cursor scatter of
// src into sorted_src.
// ---------------------------------------------------------------------------
__global__ __launch_bounds__(256) void bucket_csr(const unsigned int* __restrict__ pairs,
                                                  const int* __restrict__ ebase,
                                                  int* __restrict__ row_ptr,
                                                  int* __restrict__ sorted_src) {
    __shared__ int h[BNODES];    // counts -> exclusive scan -> cursors
    __shared__ int part[256];
    const int tid = threadIdx.x;
    const int b = blockIdx.x;
    const int base = ebase[b * P_BLOCKS];
    const int next = (b == NBUCK - 1) ? N_EDGES : ebase[(b + 1) * P_BLOCKS];
    const int cnt = next - base;
    const int n0 = b * BNODES;

    h[tid] = 0; h[tid + 256] = 0;
    __syncthreads();
    for (int i = tid; i < cnt; i += 256)
        atomicAdd(&h[pairs[base + i] & 511u], 1);
    __syncthreads();
    int a0 = h[2 * tid], a1 = h[2 * tid + 1];
    part[tid] = a0 + a1;
    __syncthreads();
    for (int st = 1; st < 256; st <<= 1) {
        int u = (tid >= st) ? part[tid - st] : 0;
        __syncthreads();
        part[tid] += u;
        __syncthreads();
    }
    int eb = part[tid] - (a0 + a1);          // exclusive base of node pair
    h[2 * tid] = eb;
    h[2 * tid + 1] = eb + a0;
    int node0 = n0 + 2 * tid;
    if (node0 <= N_NODES) row_ptr[node0] = base + eb;
    if (node0 + 1 <= N_NODES) row_ptr[node0 + 1] = base + eb + a0;
    __syncthreads();
    for (int i = tid; i < cnt; i += 256) {
        unsigned int pr = pairs[base + i];
        int p = atomicAdd(&h[pr & 511u], 1);
        sorted_src[base + p] = (int)(pr >> 9);
    }
}

// ---------------------------------------------------------------------------
// Gather core: ONE NODE PER 8-LANE GROUP, 8 nodes per wave in parallel.
// Lane (grp, q) accumulates features 8q..8q+7 of node grp -> NO cross-lane
// reduce; group writes its 128B mean row directly. PER-GROUP loop bound
// with 8-EDGE UNROLL: 8 rows + 8 idx loads in flight per group; deg<=8
// (40% of nodes) finishes in ONE latency round, deg<=16 (92%) in two.
// sorted_src zero-padded -> clamp-free; invalid slots redirect index to
// the zero sentinel row (L1-resident, free).
// ---------------------------------------------------------------------------
__device__ __forceinline__ void gather8g(
        const uint4* __restrict__ featb4,   // bf16 rows as [N][8] uint4
        const int* __restrict__ row_ptr,
        const int* __restrict__ sorted_src,
        int node0, int l, unsigned short mt[16][72], int mrow0) {
    const int grp = l >> 3;     // node slot 0..7
    const int q   = l & 7;      // uint4 within row (feats 8q..8q+7)

    int rp = 0;
    if (l <= 8) rp = row_ptr[node0 + l];   // 9 boundaries, one load
    const int start = __shfl(rp, grp);
    const int end   = __shfl(rp, grp + 1);
    const int deg   = end - start;

    float a0 = 0.f, a1 = 0.f, a2 = 0.f, a3 = 0.f,
          a4 = 0.f, a5 = 0.f, a6 = 0.f, a7 = 0.f;
    for (int j = 0; j < deg; j += 8) {     // per-group bound; masked exit
        int e0 = start + j;
        int s0 = sorted_src[e0];           // pad-safe, no clamp
        int s1 = sorted_src[e0 + 1];
        int s2 = sorted_src[e0 + 2];
        int s3 = sorted_src[e0 + 3];
        int s4 = sorted_src[e0 + 4];
        int s5 = sorted_src[e0 + 5];
        int s6 = sorted_src[e0 + 6];
        int s7 = sorted_src[e0 + 7];
        int i0 = (e0     < end) ? s0 : N_NODES;   // sentinel row = zeros
        int i1 = (e0 + 1 < end) ? s1 : N_NODES;
        int i2 = (e0 + 2 < end) ? s2 : N_NODES;
        int i3 = (e0 + 3 < end) ? s3 : N_NODES;
        int i4 = (e0 + 4 < end) ? s4 : N_NODES;
        int i5 = (e0 + 5 < end) ? s5 : N_NODES;
        int i6 = (e0 + 6 < end) ? s6 : N_NODES;
        int i7 = (e0 + 7 < end) ? s7 : N_NODES;
        uint4 w0 = featb4[i0 * 8 + q];
        uint4 w1 = featb4[i1 * 8 + q];
        uint4 w2 = featb4[i2 * 8 + q];
        uint4 w3 = featb4[i3 * 8 + q];
        uint4 w4 = featb4[i4 * 8 + q];
        uint4 w5 = featb4[i5 * 8 + q];
        uint4 w6 = featb4[i6 * 8 + q];
        uint4 w7 = featb4[i7 * 8 + q];
        a0 += ((blo(w0.x) + blo(w1.x)) + (blo(w2.x) + blo(w3.x)))
            + ((blo(w4.x) + blo(w5.x)) + (blo(w6.x) + blo(w7.x)));
        a1 += ((bhi(w0.x) + bhi(w1.x)) + (bhi(w2.x) + bhi(w3.x)))
            + ((bhi(w4.x) + bhi(w5.x)) + (bhi(w6.x) + bhi(w7.x)));
        a2 += ((blo(w0.y) + blo(w1.y)) + (blo(w2.y) + blo(w3.y)))
            + ((blo(w4.y) + blo(w5.y)) + (blo(w6.y) + blo(w7.y)));
        a3 += ((bhi(w0.y) + bhi(w1.y)) + (bhi(w2.y) + bhi(w3.y)))
            + ((bhi(w4.y) + bhi(w5.y)) + (bhi(w6.y) + bhi(w7.y)));
        a4 += ((blo(w0.z) + blo(w1.z)) + (blo(w2.z) + blo(w3.z)))
            + ((blo(w4.z) + blo(w5.z)) + (blo(w6.z) + blo(w7.z)));
        a5 += ((bhi(w0.z) + bhi(w1.z)) + (bhi(w2.z) + bhi(w3.z)))
            + ((bhi(w4.z) + bhi(w5.z)) + (bhi(w6.z) + bhi(w7.z)));
        a6 += ((blo(w0.w) + blo(w1.w)) + (blo(w2.w) + blo(w3.w)))
            + ((blo(w4.w) + blo(w5.w)) + (blo(w6.w) + blo(w7.w)));
        a7 += ((bhi(w0.w) + bhi(w1.w)) + (bhi(w2.w) + bhi(w3.w)))
            + ((bhi(w4.w) + bhi(w5.w)) + (bhi(w6.w) + bhi(w7.w)));
    }

    float inv = 1.0f / fmaxf((float)deg, 1.0f);
    uint4 o;
    o.x = pack2bf(a0 * inv, a1 * inv);
    o.y = pack2bf(a2 * inv, a3 * inv);
    o.z = pack2bf(a4 * inv, a5 * inv);
    o.w = pack2bf(a6 * inv, a7 * inv);
    *(uint4*)&mt[mrow0 + grp][q << 3] = o;   // every lane writes 16B
}

// ---------------------------------------------------------------------------
// Layer 1 fused: 2 waves per tile. Gather (8 nodes/wave, group-parallel) ->
// sync -> each wave runs 2 of the tile's 4 N-tile MFMA chains.
// ---------------------------------------------------------------------------
__global__ __launch_bounds__(256) void sage_fused(
        const uint4* __restrict__ featb4,          // xb (with zero row)
        const int* __restrict__ row_ptr,
        const int* __restrict__ sorted_src,
        const unsigned int* __restrict__ packedB,
        const float* __restrict__ bias,
        unsigned short* __restrict__ outb) {
    __shared__ __align__(16) unsigned short mt[2][16][72];
    const int wv = threadIdx.x >> 6;
    const int l  = threadIdx.x & 63;
    const int ts   = wv >> 1;                 // tile slot in block
    const int half = wv & 1;                  // which 8 nodes / which 2 N-tiles
    const int tile = blockIdx.x * 2 + ts;     // grid exact (NTILES even)

    gather8g(featb4, row_ptr, sorted_src, (tile << 4) + (half << 3), l,
             mt[ts], half << 3);
    __syncthreads();

    const int col = l & 15;
    const int g   = l >> 4;
    bf16x8 af0 = *(const bf16x8*)&mt[ts][col][g << 3];
    bf16x8 af1 = *(const bf16x8*)&mt[ts][col][32 + (g << 3)];
    const unsigned int* srw = (const unsigned int*)featb4 + ((tile << 4) + col) * 32;
    bf16x8 af2 = *(const bf16x8*)(srw + (g << 2));
    bf16x8 af3 = *(const bf16x8*)(srw + 16 + (g << 2));

#pragma unroll
    for (int nn = 0; nn < 2; ++nn) {
        const int n = (half << 1) | nn;
        bf16x8 b0 = *(const bf16x8*)(packedB + (((0 * 4 + n) * 64 + l) << 2));
        bf16x8 b1 = *(const bf16x8*)(packedB + (((1 * 4 + n) * 64 + l) << 2));
        bf16x8 b2 = *(const bf16x8*)(packedB + (((2 * 4 + n) * 64 + l) << 2));
        bf16x8 b3 = *(const bf16x8*)(packedB + (((3 * 4 + n) * 64 + l) << 2));
        f32x4 a = {0.f, 0.f, 0.f, 0.f};
        a = __builtin_amdgcn_mfma_f32_16x16x32_bf16(af0, b0, a, 0, 0, 0);
        a = __builtin_amdgcn_mfma_f32_16x16x32_bf16(af1, b1, a, 0, 0, 0);
        a = __builtin_amdgcn_mfma_f32_16x16x32_bf16(af2, b2, a, 0, 0, 0);
        a = __builtin_amdgcn_mfma_f32_16x16x32_bf16(af3, b3, a, 0, 0, 0);
        const int j = (n << 4) | col;
        const float bj = bias[j];
#pragma unroll
        for (int r = 0; r < 4; ++r) {
            int node = (tile << 4) + (g << 2) + r;
            outb[node * 64 + j] = f2bf(fmaxf(a[r] + bj, 0.f));
        }
    }
}

// ---------------------------------------------------------------------------
// Layer 2 fused + output projection: same 2-wave-per-tile structure; h2
// tile assembled in LDS (both waves write their column halves), then the
// even wave of each pair runs the K=64 projection MFMAs. No h2 buffer.
// ---------------------------------------------------------------------------
__global__ __launch_bounds__(256) void sage_fused_out(
        const uint4* __restrict__ featb4,           // h1b (with zero row)
        const int* __restrict__ row_ptr,
        const int* __restrict__ sorted_src,
        const unsigned int* __restrict__ packedB,   // layer-2 weights
        const float* __restrict__ bias,             // b2
        const unsigned int* __restrict__ packedBo,  // 512 dwords
        const float* __restrict__ bout,
        float* __restrict__ out) {
    __shared__ __align__(16) unsigned short mt[2][16][72];
    __shared__ __align__(16) unsigned short ht[2][16][72];
    const int wv = threadIdx.x >> 6;
    const int l  = threadIdx.x & 63;
    const int ts   = wv >> 1;
    const int half = wv & 1;
    const int tile = blockIdx.x * 2 + ts;

    gather8g(featb4, row_ptr, sorted_src, (tile << 4) + (half << 3), l,
             mt[ts], half << 3);
    __syncthreads();

    const int col = l & 15;
    const int g   = l >> 4;
    bf16x8 af0 = *(const bf16x8*)&mt[ts][col][g << 3];
    bf16x8 af1 = *(const bf16x8*)&mt[ts][col][32 + (g << 3)];
    const unsigned int* srw = (const unsigned int*)featb4 + ((tile << 4) + col) * 32;
    bf16x8 af2 = *(const bf16x8*)(srw + (g << 2));
    bf16x8 af3 = *(const bf16x8*)(srw + 16 + (g << 2));

#pragma unroll
    for (int nn = 0; nn < 2; ++nn) {
        const int n = (half << 1) | nn;
        bf16x8 b0 = *(const bf16x8*)(packedB + (((0 * 4 + n) * 64 + l) << 2));
        bf16x8 b1 = *(const bf16x8*)(packedB + (((1 * 4 + n) * 64 + l) << 2));
        bf16x8 b2 = *(const bf16x8*)(packedB + (((2 * 4 + n) * 64 + l) << 2));
        bf16x8 b3 = *(const bf16x8*)(packedB + (((3 * 4 + n) * 64 + l) << 2));
        f32x4 a = {0.f, 0.f, 0.f, 0.f};
        a = __builtin_amdgcn_mfma_f32_16x16x32_bf16(af0, b0, a, 0, 0, 0);
        a = __builtin_amdgcn_mfma_f32_16x16x32_bf16(af1, b1, a, 0, 0, 0);
        a = __builtin_amdgcn_mfma_f32_16x16x32_bf16(af2, b2, a, 0, 0, 0);
        a = __builtin_amdgcn_mfma_f32_16x16x32_bf16(af3, b3, a, 0, 0, 0);
        const int j = (n << 4) | col;
        const float bj = bias[j];
#pragma unroll
        for (int r = 0; r < 4; ++r)
            ht[ts][(g << 2) + r][j] = f2bf(fmaxf(a[r] + bj, 0.f));
    }
    __syncthreads();

    if (half == 0) {   // even wave of each pair projects its tile
        bf16x8 bo0 = *(const bf16x8*)(packedBo + (l << 2));
        bf16x8 bo1 = *(const bf16x8*)(packedBo + ((64 + l) << 2));
        bf16x8 ha0 = *(const bf16x8*)&ht[ts][col][g << 3];
        bf16x8 ha1 = *(const bf16x8*)&ht[ts][col][32 + (g << 3)];

        f32x4 acc2 = {0.f, 0.f, 0.f, 0.f};
        acc2 = __builtin_amdgcn_mfma_f32_16x16x32_bf16(ha0, bo0, acc2, 0, 0, 0);
        acc2 = __builtin_amdgcn_mfma_f32_16x16x32_bf16(ha1, bo1, acc2, 0, 0, 0);

        if (col < NCLS) {
            float bj = bout[col];
#pragma unroll
            for (int r = 0; r < 4; ++r)
                out[((tile << 4) + (g << 2) + r) * NCLS + col] = acc2[r] + bj;
        }
    }
}

// ---------------------------------------------------------------------------
extern "C" void kernel_launch(void* const* d_in, const int* in_sizes, int n_in,
                              void* d_out, int out_size, void* d_ws, size_t ws_size,
                              hipStream_t stream) {
    const float* x   = (const float*)d_in[0];
    const int*   ei  = (const int*)d_in[1];   // [2, N_EDGES]
    const int*   src = ei;
    const int*   dst = ei + N_EDGES;
    const float* W1l = (const float*)d_in[2];
    const float* W1r = (const float*)d_in[3];
    const float* b1  = (const float*)d_in[4];
    const float* W2l = (const float*)d_in[5];
    const float* W2r = (const float*)d_in[6];
    const float* b2  = (const float*)d_in[7];
    const float* Wo  = (const float*)d_in[8];
    const float* bo  = (const float*)d_in[9];
    float* out = (float*)d_out;

    char* ws = (char*)d_ws;
    int*   histG      = (int*)(ws + 0x0000000);  // 50176 ints
    int*   scanP      = (int*)(ws + 0x0040000);  // 196 ints
    int*   ebase      = (int*)(ws + 0x0044000);  // 50176 ints
    int*   row_ptr    = (int*)(ws + 0x0080000);  // 100001 ints
    unsigned int* pairs = (unsigned int*)(ws + 0x0100000);     // 4 MB (packed)
    int*   sorted_src = (int*)(ws + 0x0500000);                // 4 MB + 32B pad
    unsigned short* xb  = (unsigned short*)(ws + 0x0900000);   // 12.8 MB + zero row
    unsigned short* h1b = (unsigned short*)(ws + 0x1540000);   // 12.8 MB + zero row
    unsigned int* packedB1 = (unsigned int*)(ws + 0x2180000);  // 16 KB
    unsigned int* packedB2 = (unsigned int*)(ws + 0x2184000);  // 16 KB
    unsigned int* packedBo = (unsigned int*)(ws + 0x2188000);  // 2 KB

    const int layer_blocks = NTILES / 2;               // 3125, exact
    const int hp_blocks    = P_BLOCKS + CVT_BLOCKS + 32 + 2 + 1;  // 6541

    // ---- CSR build + prep (5 dispatches) ----
    hist_prep<<<hp_blocks, 256, 0, stream>>>(dst, histG, x, W1l, W1r, W2l, W2r,
                                             Wo, xb, h1b, sorted_src,
                                             packedB1, packedB2, packedBo);
    scan_partials<<<NBUCK, 256, 0, stream>>>(histG, scanP);
    scan_final<<<NBUCK, 256, 0, stream>>>(histG, scanP, ebase);
    edge_partition<<<P_BLOCKS, 256, 0, stream>>>(src, dst, ebase, pairs);
    bucket_csr<<<NBUCK, 256, 0, stream>>>(pairs, ebase, row_ptr, sorted_src);

    // ---- layer 1 (fused gather+MFMA, group-parallel gather) ----
    sage_fused<<<layer_blocks, 256, 0, stream>>>((const uint4*)xb, row_ptr,
                                                 sorted_src, packedB1, b1, h1b);

    // ---- layer 2 + output projection (fused) ----
    sage_fused_out<<<layer_blocks, 256, 0, stream>>>((const uint4*)h1b, row_ptr,
                                                     sorted_src, packedB2, b2,
                                                     packedBo, bo, out);
}

// Round 20
// 92.596 us; speedup vs baseline: 1.0911x; 1.0413x over previous
//
#include <hip/hip_runtime.h>

#define N_NODES 100000
#define N_EDGES 1000000
#define D 64
#define NCLS 10
#define NTILES (N_NODES / 16)   // 6250, exact (even -> 2 tiles/block exact)

#define NBUCK 196            // buckets of 512 nodes: bucket = dst >> 9
#define BNODES 512
#define P_BLOCKS 256         // partition blocks
#define P_EPB 3907           // edges per partition block; 256*3907 >= 1M

#define CVT_BLOCKS (N_NODES * D / 4 / 256)   // 6250, exact

typedef __attribute__((ext_vector_type(8))) short bf16x8;   // 8 bf16 = 4 VGPR
typedef __attribute__((ext_vector_type(4))) float f32x4;

// round-to-nearest-even f32 -> bf16 bits
__device__ __forceinline__ unsigned short f2bf(float x) {
    unsigned int u = __float_as_uint(x);
    u += 0x7fffu + ((u >> 16) & 1u);
    return (unsigned short)(u >> 16);
}
__device__ __forceinline__ unsigned int pack2bf(float lo, float hi) {
    return (unsigned int)f2bf(lo) | ((unsigned int)f2bf(hi) << 16);
}
__device__ __forceinline__ float blo(unsigned int u) { return __uint_as_float(u << 16); }
__device__ __forceinline__ float bhi(unsigned int u) { return __uint_as_float(u & 0xffff0000u); }

// ---------------------------------------------------------------------------
// Kernel 1 (merged): blocks 0..255 -> per-(block,bucket) edge histogram;
// then prep blocks (bf16 table + weight packs); last block zeroes the
// sentinel row N_NODES of both feature tables AND the sorted_src pad.
// ---------------------------------------------------------------------------
__global__ __launch_bounds__(256) void hist_prep(const int* __restrict__ dst,
                                                 int* __restrict__ histG,
                                                 const float* __restrict__ x,
                                                 const float* __restrict__ W1l,
                                                 const float* __restrict__ W1r,
                                                 const float* __restrict__ W2l,
                                                 const float* __restrict__ W2r,
                                                 const float* __restrict__ Wout,
                                                 unsigned short* __restrict__ xb,
                                                 unsigned short* __restrict__ h1b,
                                                 int* __restrict__ sorted_src,
                                                 unsigned int* __restrict__ pB1,
                                                 unsigned int* __restrict__ pB2,
                                                 unsigned int* __restrict__ pBo) {
    const int tid = threadIdx.x;
    if (blockIdx.x < P_BLOCKS) {                 // ---- edge histogram ----
        __shared__ int lh[256];
        lh[tid] = 0;
        __syncthreads();
        const int e0 = blockIdx.x * P_EPB;
        int ecnt = N_EDGES - e0;
        if (ecnt > P_EPB) ecnt = P_EPB;
        if (ecnt < 0) ecnt = 0;
        for (int i = tid; i < ecnt; i += 256)
            atomicAdd(&lh[dst[e0 + i] >> 9], 1);   // LDS atomic
        __syncthreads();
        if (tid < NBUCK) histG[tid * P_BLOCKS + blockIdx.x] = lh[tid];
        return;
    }
    const int b = blockIdx.x - P_BLOCKS;
    if (b < CVT_BLOCKS) {                        // ---- x -> bf16 table ----
        int i = b * 256 + tid;                   // float4 index, exact bound
        float4 v = ((const float4*)x)[i];
        ushort4 o;
        o.x = f2bf(v.x); o.y = f2bf(v.y); o.z = f2bf(v.z); o.w = f2bf(v.w);
        ((ushort4*)xb)[i] = o;
    } else if (b < CVT_BLOCKS + 32) {            // ---- SAGE weight packs ----
        int wsel = (b - CVT_BLOCKS) >> 4;
        const float* Wl = wsel ? W2l : W1l;
        const float* Wr = wsel ? W2r : W1r;
        unsigned int* pB = wsel ? pB2 : pB1;
        int idx = ((b - CVT_BLOCKS) & 15) * 256 + tid;   // 0..4095
        int r    = idx & 3;
        int lane = (idx >> 2) & 63;
        int n    = (idx >> 8) & 3;
        int t    = idx >> 10;
        int j  = n * 16 + (lane & 15);
        int k0 = t * 32 + ((lane >> 4) << 3) + 2 * r;
        float lo = (k0 < 64) ? Wl[j * 64 + k0] : Wr[j * 64 + (k0 - 64)];
        float hi = (k0 + 1 < 64) ? Wl[j * 64 + k0 + 1] : Wr[j * 64 + (k0 - 63)];
        pB[idx] = pack2bf(lo, hi);
    } else if (b < CVT_BLOCKS + 34) {            // ---- W_out pack ----
        int idx = (b - CVT_BLOCKS - 32) * 256 + tid;
        if (idx < 512) {
            int r    = idx & 3;
            int lane = (idx >> 2) & 63;
            int t    = idx >> 8;
            int j  = lane & 15;
            int k0 = t * 32 + ((lane >> 4) << 3) + 2 * r;
            float lo = (j < NCLS) ? Wout[j * 64 + k0] : 0.f;
            float hi = (j < NCLS) ? Wout[j * 64 + k0 + 1] : 0.f;
            pBo[idx] = pack2bf(lo, hi);
        }
    } else {                                     // ---- sentinels ----
        if (tid < 64) {
            xb[N_NODES * 64 + tid] = 0;
            h1b[N_NODES * 64 + tid] = 0;
        }
        if (tid < 16) sorted_src[N_EDGES + tid] = 0;   // pad: clamp-free reads
    }
}

// ---------------------------------------------------------------------------
// Kernel 2: per-256-chunk sums of histG rows (196 blocks).
// ---------------------------------------------------------------------------
__global__ __launch_bounds__(256) void scan_partials(const int* __restrict__ in,
                                                     int* __restrict__ blockSum) {
    __shared__ int s[256];
    s[threadIdx.x] = in[blockIdx.x * 256 + threadIdx.x];
    __syncthreads();
    for (int st = 128; st > 0; st >>= 1) {
        if (threadIdx.x < st) s[threadIdx.x] += s[threadIdx.x + st];
        __syncthreads();
    }
    if (threadIdx.x == 0) blockSum[blockIdx.x] = s[0];
}

// ---------------------------------------------------------------------------
// Kernel 3: full exclusive scan -> ebase (each block re-scans 196 row totals).
// ---------------------------------------------------------------------------
__global__ __launch_bounds__(256) void scan_final(const int* __restrict__ in,
                                                  const int* __restrict__ blockSum,
                                                  int* __restrict__ ebase) {
    __shared__ int p[256];
    __shared__ int s[256];
    const int t = threadIdx.x;
    int pv = (t < NBUCK) ? blockSum[t] : 0;
    p[t] = pv;
    __syncthreads();
    for (int st = 1; st < 256; st <<= 1) {
        int u = (t >= st) ? p[t - st] : 0;
        __syncthreads();
        p[t] += u;
        __syncthreads();
    }
    const int rowOff = (blockIdx.x > 0) ? p[blockIdx.x - 1] : 0;
    const int i = blockIdx.x * 256 + t;
    int v = in[i];
    s[t] = v;
    __syncthreads();
    for (int st = 1; st < 256; st <<= 1) {
        int u = (t >= st) ? s[t - st] : 0;
        __syncthreads();
        s[t] += u;
        __syncthreads();
    }
    ebase[i] = s[t] - v + rowOff;
}

// ---------------------------------------------------------------------------
// Kernel 4: partition edges into bucket-sorted packed array.
// Packed record: (src<<9)|(dst&511).
// ---------------------------------------------------------------------------
__global__ __launch_bounds__(256) void edge_partition(const int* __restrict__ src,
                                                      const int* __restrict__ dst,
                                                      const int* __restrict__ ebase,
                                                      unsigned int* __restrict__ pairs) {
    __shared__ int s[256];
    __shared__ int lbase[256];
    __shared__ int lcur[256];
    __shared__ uint2 buf[P_EPB];     // 31.2 KB
    const int tid = threadIdx.x;
    const int e0 = blockIdx.x * P_EPB;
    int ecnt = N_EDGES - e0;
    if (ecnt > P_EPB) ecnt = P_EPB;
    if (ecnt < 0) ecnt = 0;

    lcur[tid] = 0;
    __syncthreads();
    for (int i = tid; i < ecnt; i += 256)
        atomicAdd(&lcur[dst[e0 + i] >> 9], 1);
    __syncthreads();
    int v = lcur[tid];
    s[tid] = v;
    __syncthreads();
    for (int st = 1; st < 256; st <<= 1) {
        int u = (tid >= st) ? s[tid - st] : 0;
        __syncthreads();
        s[tid] += u;
        __syncthreads();
    }
    int excl = s[tid] - v;
    lbase[tid] = excl;
    lcur[tid] = excl;
    __syncthreads();
    for (int i = tid; i < ecnt; i += 256) {
        int d = dst[e0 + i], sv = src[e0 + i];
        int p = atomicAdd(&lcur[d >> 9], 1);
        buf[p] = make_uint2((unsigned)sv, (unsigned)d);
    }
    __syncthreads();
    for (int i = tid; i < ecnt; i += 256) {
        uint2 pr = buf[i];
        int bk = (int)(pr.y >> 9);
        pairs[ebase[bk * P_BLOCKS + blockIdx.x] + (i - lbase[bk])] =
            (pr.x << 9) | (pr.y & 511u);
    }
}

// ---------------------------------------------------------------------------
// Kernel 5: per-bucket node hist + scan -> row_ptr; LDS-cursor scatter of
// src into sorted_src.
// ---------------------------------------------------------------------------
__global__ __launch_bounds__(256) void bucket_csr(const unsigned int* __restrict__ pairs,
                                                  const int* __restrict__ ebase,
                                                  int* __restrict__ row_ptr,
                                                  int* __restrict__ sorted_src) {
    __shared__ int h[BNODES];    // counts -> exclusive scan -> cursors
    __shared__ int part[256];
    const int tid = threadIdx.x;
    const int b = blockIdx.x;
    const int base = ebase[b * P_BLOCKS];
    const int next = (b == NBUCK - 1) ? N_EDGES : ebase[(b + 1) * P_BLOCKS];
    const int cnt = next - base;
    const int n0 = b * BNODES;

    h[tid] = 0; h[tid + 256] = 0;
    __syncthreads();
    for (int i = tid; i < cnt; i += 256)
        atomicAdd(&h[pairs[base + i] & 511u], 1);
    __syncthreads();
    int a0 = h[2 * tid], a1 = h[2 * tid + 1];
    part[tid] = a0 + a1;
    __syncthreads();
    for (int st = 1; st < 256; st <<= 1) {
        int u = (tid >= st) ? part[tid - st] : 0;
        __syncthreads();
        part[tid] += u;
        __syncthreads();
    }
    int eb = part[tid] - (a0 + a1);          // exclusive base of node pair
    h[2 * tid] = eb;
    h[2 * tid + 1] = eb + a0;
    int node0 = n0 + 2 * tid;
    if (node0 <= N_NODES) row_ptr[node0] = base + eb;
    if (node0 + 1 <= N_NODES) row_ptr[node0 + 1] = base + eb + a0;
    __syncthreads();
    for (int i = tid; i < cnt; i += 256) {
        unsigned int pr = pairs[base + i];
        int p = atomicAdd(&h[pr & 511u], 1);
        sorted_src[base + p] = (int)(pr >> 9);
    }
}

// ---------------------------------------------------------------------------
// Gather core: ONE NODE PER 8-LANE GROUP, 8 nodes per wave in parallel;
// NO cross-lane reduce. 8-edge unroll with SOFTWARE-PIPELINED idx loads:
// batch j+8's 8 index loads issue concurrently with batch j's feature-row
// loads -> steady state is ONE latency round per 8-edge batch (was two).
// sorted_src zero-padded (16 entries) -> all idx loads clamp-free.
// Invalid slots redirect the index to the zero sentinel row.
// ---------------------------------------------------------------------------
__device__ __forceinline__ void gather8g(
        const uint4* __restrict__ featb4,   // bf16 rows as [N][8] uint4
        const int* __restrict__ row_ptr,
        const int* __restrict__ sorted_src,
        int node0, int l, unsigned short mt[16][72], int mrow0) {
    const int grp = l >> 3;     // node slot 0..7
    const int q   = l & 7;      // uint4 within row (feats 8q..8q+7)

    int rp = 0;
    if (l <= 8) rp = row_ptr[node0 + l];   // 9 boundaries, one load
    const int start = __shfl(rp, grp);
    const int end   = __shfl(rp, grp + 1);
    const int deg   = end - start;

    // prefetch idx batch 0 (pad-safe: start+7 <= N_EDGES+7 < padded size)
    int s0 = sorted_src[start];
    int s1 = sorted_src[start + 1];
    int s2 = sorted_src[start + 2];
    int s3 = sorted_src[start + 3];
    int s4 = sorted_src[start + 4];
    int s5 = sorted_src[start + 5];
    int s6 = sorted_src[start + 6];
    int s7 = sorted_src[start + 7];

    float a0 = 0.f, a1 = 0.f, a2 = 0.f, a3 = 0.f,
          a4 = 0.f, a5 = 0.f, a6 = 0.f, a7 = 0.f;
    for (int j = 0; j < deg; j += 8) {     // per-group bound; masked exit
        const int e0 = start + j;
        int i0 = (e0     < end) ? s0 : N_NODES;   // sentinel row = zeros
        int i1 = (e0 + 1 < end) ? s1 : N_NODES;
        int i2 = (e0 + 2 < end) ? s2 : N_NODES;
        int i3 = (e0 + 3 < end) ? s3 : N_NODES;
        int i4 = (e0 + 4 < end) ? s4 : N_NODES;
        int i5 = (e0 + 5 < end) ? s5 : N_NODES;
        int i6 = (e0 + 6 < end) ? s6 : N_NODES;
        int i7 = (e0 + 7 < end) ? s7 : N_NODES;
        uint4 w0 = featb4[i0 * 8 + q];
        uint4 w1 = featb4[i1 * 8 + q];
        uint4 w2 = featb4[i2 * 8 + q];
        uint4 w3 = featb4[i3 * 8 + q];
        uint4 w4 = featb4[i4 * 8 + q];
        uint4 w5 = featb4[i5 * 8 + q];
        uint4 w6 = featb4[i6 * 8 + q];
        uint4 w7 = featb4[i7 * 8 + q];
        // prefetch next idx batch; overlaps the feature-row loads above
        // (pad-safe: e8 < end <= N_EDGES -> e8+7 <= N_EDGES+6 < padded size)
        const int e8 = e0 + 8;
        if (e8 < end) {
            s0 = sorted_src[e8];
            s1 = sorted_src[e8 + 1];
            s2 = sorted_src[e8 + 2];
            s3 = sorted_src[e8 + 3];
            s4 = sorted_src[e8 + 4];
            s5 = sorted_src[e8 + 5];
            s6 = sorted_src[e8 + 6];
            s7 = sorted_src[e8 + 7];
        }
        a0 += ((blo(w0.x) + blo(w1.x)) + (blo(w2.x) + blo(w3.x)))
            + ((blo(w4.x) + blo(w5.x)) + (blo(w6.x) + blo(w7.x)));
        a1 += ((bhi(w0.x) + bhi(w1.x)) + (bhi(w2.x) + bhi(w3.x)))
            + ((bhi(w4.x) + bhi(w5.x)) + (bhi(w6.x) + bhi(w7.x)));
        a2 += ((blo(w0.y) + blo(w1.y)) + (blo(w2.y) + blo(w3.y)))
            + ((blo(w4.y) + blo(w5.y)) + (blo(w6.y) + blo(w7.y)));
        a3 += ((bhi(w0.y) + bhi(w1.y)) + (bhi(w2.y) + bhi(w3.y)))
            + ((bhi(w4.y) + bhi(w5.y)) + (bhi(w6.y) + bhi(w7.y)));
        a4 += ((blo(w0.z) + blo(w1.z)) + (blo(w2.z) + blo(w3.z)))
            + ((blo(w4.z) + blo(w5.z)) + (blo(w6.z) + blo(w7.z)));
        a5 += ((bhi(w0.z) + bhi(w1.z)) + (bhi(w2.z) + bhi(w3.z)))
            + ((bhi(w4.z) + bhi(w5.z)) + (bhi(w6.z) + bhi(w7.z)));
        a6 += ((blo(w0.w) + blo(w1.w)) + (blo(w2.w) + blo(w3.w)))
            + ((blo(w4.w) + blo(w5.w)) + (blo(w6.w) + blo(w7.w)));
        a7 += ((bhi(w0.w) + bhi(w1.w)) + (bhi(w2.w) + bhi(w3.w)))
            + ((bhi(w4.w) + bhi(w5.w)) + (bhi(w6.w) + bhi(w7.w)));
    }

    float inv = 1.0f / fmaxf((float)deg, 1.0f);
    uint4 o;
    o.x = pack2bf(a0 * inv, a1 * inv);
    o.y = pack2bf(a2 * inv, a3 * inv);
    o.z = pack2bf(a4 * inv, a5 * inv);
    o.w = pack2bf(a6 * inv, a7 * inv);
    *(uint4*)&mt[mrow0 + grp][q << 3] = o;   // every lane writes 16B
}

// ---------------------------------------------------------------------------
// Layer 1 fused: 2 waves per tile. Gather (8 nodes/wave, group-parallel) ->
// sync -> each wave runs 2 of the tile's 4 N-tile MFMA chains.
// ---------------------------------------------------------------------------
__global__ __launch_bounds__(256) void sage_fused(
        const uint4* __restrict__ featb4,          // xb (with zero row)
        const int* __restrict__ row_ptr,
        const int* __restrict__ sorted_src,
        const unsigned int* __restrict__ packedB,
        const float* __restrict__ bias,
        unsigned short* __restrict__ outb) {
    __shared__ __align__(16) unsigned short mt[2][16][72];
    const int wv = threadIdx.x >> 6;
    const int l  = threadIdx.x & 63;
    const int ts   = wv >> 1;                 // tile slot in block
    const int half = wv & 1;                  // which 8 nodes / which 2 N-tiles
    const int tile = blockIdx.x * 2 + ts;     // grid exact (NTILES even)

    gather8g(featb4, row_ptr, sorted_src, (tile << 4) + (half << 3), l,
             mt[ts], half << 3);
    __syncthreads();

    const int col = l & 15;
    const int g   = l >> 4;
    bf16x8 af0 = *(const bf16x8*)&mt[ts][col][g << 3];
    bf16x8 af1 = *(const bf16x8*)&mt[ts][col][32 + (g << 3)];
    const unsigned int* srw = (const unsigned int*)featb4 + ((tile << 4) + col) * 32;
    bf16x8 af2 = *(const bf16x8*)(srw + (g << 2));
    bf16x8 af3 = *(const bf16x8*)(srw + 16 + (g << 2));

#pragma unroll
    for (int nn = 0; nn < 2; ++nn) {
        const int n = (half << 1) | nn;
        bf16x8 b0 = *(const bf16x8*)(packedB + (((0 * 4 + n) * 64 + l) << 2));
        bf16x8 b1 = *(const bf16x8*)(packedB + (((1 * 4 + n) * 64 + l) << 2));
        bf16x8 b2 = *(const bf16x8*)(packedB + (((2 * 4 + n) * 64 + l) << 2));
        bf16x8 b3 = *(const bf16x8*)(packedB + (((3 * 4 + n) * 64 + l) << 2));
        f32x4 a = {0.f, 0.f, 0.f, 0.f};
        a = __builtin_amdgcn_mfma_f32_16x16x32_bf16(af0, b0, a, 0, 0, 0);
        a = __builtin_amdgcn_mfma_f32_16x16x32_bf16(af1, b1, a, 0, 0, 0);
        a = __builtin_amdgcn_mfma_f32_16x16x32_bf16(af2, b2, a, 0, 0, 0);
        a = __builtin_amdgcn_mfma_f32_16x16x32_bf16(af3, b3, a, 0, 0, 0);
        const int j = (n << 4) | col;
        const float bj = bias[j];
#pragma unroll
        for (int r = 0; r < 4; ++r) {
            int node = (tile << 4) + (g << 2) + r;
            outb[node * 64 + j] = f2bf(fmaxf(a[r] + bj, 0.f));
        }
    }
}

// ---------------------------------------------------------------------------
// Layer 2 fused + output projection: same 2-wave-per-tile structure; h2
// tile assembled in LDS (both waves write their column halves), then the
// even wave of each pair runs the K=64 projection MFMAs. No h2 buffer.
// ---------------------------------------------------------------------------
__global__ __launch_bounds__(256) void sage_fused_out(
        const uint4* __restrict__ featb4,           // h1b (with zero row)
        const int* __restrict__ row_ptr,
        const int* __restrict__ sorted_src,
        const unsigned int* __restrict__ packedB,   // layer-2 weights
        const float* __restrict__ bias,             // b2
        const unsigned int* __restrict__ packedBo,  // 512 dwords
        const float* __restrict__ bout,
        float* __restrict__ out) {
    __shared__ __align__(16) unsigned short mt[2][16][72];
    __shared__ __align__(16) unsigned short ht[2][16][72];
    const int wv = threadIdx.x >> 6;
    const int l  = threadIdx.x & 63;
    const int ts   = wv >> 1;
    const int half = wv & 1;
    const int tile = blockIdx.x * 2 + ts;

    gather8g(featb4, row_ptr, sorted_src, (tile << 4) + (half << 3), l,
             mt[ts], half << 3);
    __syncthreads();

    const int col = l & 15;
    const int g   = l >> 4;
    bf16x8 af0 = *(const bf16x8*)&mt[ts][col][g << 3];
    bf16x8 af1 = *(const bf16x8*)&mt[ts][col][32 + (g << 3)];
    const unsigned int* srw = (const unsigned int*)featb4 + ((tile << 4) + col) * 32;
    bf16x8 af2 = *(const bf16x8*)(srw + (g << 2));
    bf16x8 af3 = *(const bf16x8*)(srw + 16 + (g << 2));

#pragma unroll
    for (int nn = 0; nn < 2; ++nn) {
        const int n = (half << 1) | nn;
        bf16x8 b0 = *(const bf16x8*)(packedB + (((0 * 4 + n) * 64 + l) << 2));
        bf16x8 b1 = *(const bf16x8*)(packedB + (((1 * 4 + n) * 64 + l) << 2));
        bf16x8 b2 = *(const bf16x8*)(packedB + (((2 * 4 + n) * 64 + l) << 2));
        bf16x8 b3 = *(const bf16x8*)(packedB + (((3 * 4 + n) * 64 + l) << 2));
        f32x4 a = {0.f, 0.f, 0.f, 0.f};
        a = __builtin_amdgcn_mfma_f32_16x16x32_bf16(af0, b0, a, 0, 0, 0);
        a = __builtin_amdgcn_mfma_f32_16x16x32_bf16(af1, b1, a, 0, 0, 0);
        a = __builtin_amdgcn_mfma_f32_16x16x32_bf16(af2, b2, a, 0, 0, 0);
        a = __builtin_amdgcn_mfma_f32_16x16x32_bf16(af3, b3, a, 0, 0, 0);
        const int j = (n << 4) | col;
        const float bj = bias[j];
#pragma unroll
        for (int r = 0; r < 4; ++r)
            ht[ts][(g << 2) + r][j] = f2bf(fmaxf(a[r] + bj, 0.f));
    }
    __syncthreads();

    if (half == 0) {   // even wave of each pair projects its tile
        bf16x8 bo0 = *(const bf16x8*)(packedBo + (l << 2));
        bf16x8 bo1 = *(const bf16x8*)(packedBo + ((64 + l) << 2));
        bf16x8 ha0 = *(const bf16x8*)&ht[ts][col][g << 3];
        bf16x8 ha1 = *(const bf16x8*)&ht[ts][col][32 + (g << 3)];

        f32x4 acc2 = {0.f, 0.f, 0.f, 0.f};
        acc2 = __builtin_amdgcn_mfma_f32_16x16x32_bf16(ha0, bo0, acc2, 0, 0, 0);
        acc2 = __builtin_amdgcn_mfma_f32_16x16x32_bf16(ha1, bo1, acc2, 0, 0, 0);

        if (col < NCLS) {
            float bj = bout[col];
#pragma unroll
            for (int r = 0; r < 4; ++r)
                out[((tile << 4) + (g << 2) + r) * NCLS + col] = acc2[r] + bj;
        }
    }
}

// ---------------------------------------------------------------------------
extern "C" void kernel_launch(void* const* d_in, const int* in_sizes, int n_in,
                              void* d_out, int out_size, void* d_ws, size_t ws_size,
                              hipStream_t stream) {
    const float* x   = (const float*)d_in[0];
    const int*   ei  = (const int*)d_in[1];   // [2, N_EDGES]
    const int*   src = ei;
    const int*   dst = ei + N_EDGES;
    const float* W1l = (const float*)d_in[2];
    const float* W1r = (const float*)d_in[3];
    const float* b1  = (const float*)d_in[4];
    const float* W2l = (const float*)d_in[5];
    const float* W2r = (const float*)d_in[6];
    const float* b2  = (const float*)d_in[7];
    const float* Wo  = (const float*)d_in[8];
    const float* bo  = (const float*)d_in[9];
    float* out = (float*)d_out;

    char* ws = (char*)d_ws;
    int*   histG      = (int*)(ws + 0x0000000);  // 50176 ints
    int*   scanP      = (int*)(ws + 0x0040000);  // 196 ints
    int*   ebase      = (int*)(ws + 0x0044000);  // 50176 ints
    int*   row_ptr    = (int*)(ws + 0x0080000);  // 100001 ints
    unsigned int* pairs = (unsigned int*)(ws + 0x0100000);     // 4 MB (packed)
    int*   sorted_src = (int*)(ws + 0x0500000);                // 4 MB + 64B pad
    unsigned short* xb  = (unsigned short*)(ws + 0x0900000);   // 12.8 MB + zero row
    unsigned short* h1b = (unsigned short*)(ws + 0x1540000);   // 12.8 MB + zero row
    unsigned int* packedB1 = (unsigned int*)(ws + 0x2180000);  // 16 KB
    unsigned int* packedB2 = (unsigned int*)(ws + 0x2184000);  // 16 KB
    unsigned int* packedBo = (unsigned int*)(ws + 0x2188000);  // 2 KB

    const int layer_blocks = NTILES / 2;               // 3125, exact
    const int hp_blocks    = P_BLOCKS + CVT_BLOCKS + 32 + 2 + 1;  // 6541

    // ---- CSR build + prep (5 dispatches) ----
    hist_prep<<<hp_blocks, 256, 0, stream>>>(dst, histG, x, W1l, W1r, W2l, W2r,
                                             Wo, xb, h1b, sorted_src,
                                             packedB1, packedB2, packedBo);
    scan_partials<<<NBUCK, 256, 0, stream>>>(histG, scanP);
    scan_final<<<NBUCK, 256, 0, stream>>>(histG, scanP, ebase);
    edge_partition<<<P_BLOCKS, 256, 0, stream>>>(src, dst, ebase, pairs);
    bucket_csr<<<NBUCK, 256, 0, stream>>>(pairs, ebase, row_ptr, sorted_src);

    // ---- layer 1 (fused gather+MFMA, pipelined group-parallel gather) ----
    sage_fused<<<layer_blocks, 256, 0, stream>>>((const uint4*)xb, row_ptr,
                                                 sorted_src, packedB1, b1, h1b);

    // ---- layer 2 + output projection (fused) ----
    sage_fused_out<<<layer_blocks, 256, 0, stream>>>((const uint4*)h1b, row_ptr,
                                                     sorted_src, packedB2, b2,
                                                     packedBo, bo, out);
}